// Round 10
// baseline (277.546 us; speedup 1.0000x reference)
//
#include <hip/hip_runtime.h>
#include <hip/hip_fp16.h>

typedef unsigned short u16;
typedef _Float16 half8 __attribute__((ext_vector_type(8)));
typedef float floatx4 __attribute__((ext_vector_type(4)));

#define C_DIM 256
#define P_DIM 2048
#define L_DIM 1024
#define N_DIM 16
#define KEEP 102
#define QTR_PIX 4096    // pixels per quarter-pass
#define SCALE 256.0f    // 2^8 input pre-scale; both operands scaled -> acc at 2^16.
                        // Downstream is scale-invariant (topk order + w/Sum(w)).

__device__ __forceinline__ void st8(u16* dst, const u16* s) {
  uint4 u;
  u.x = (unsigned)s[0] | ((unsigned)s[1] << 16);
  u.y = (unsigned)s[2] | ((unsigned)s[3] << 16);
  u.z = (unsigned)s[4] | ((unsigned)s[5] << 16);
  u.w = (unsigned)s[6] | ((unsigned)s[7] << 16);
  *(uint4*)dst = u;
}

// fp32 -> fp16 with flush-to-zero of subnormal results (MFMA denormal guard).
__device__ __forceinline__ u16 f2h_ftz(float v) {
  if (fabsf(v) < 6.103515625e-5f) return 0;
  return __half_as_ushort(__float2half(v));
}

// async global->LDS, 16B per lane. LDS dest is wave-uniform base + lane*16.
__device__ __forceinline__ void gl_lds16(const u16* g, u16* l) {
  __builtin_amdgcn_global_load_lds(
      (const __attribute__((address_space(1))) unsigned int*)g,
      (__attribute__((address_space(3))) unsigned int*)l, 16, 0, 0);
}

// shared-memory overlay: both roles use exactly 32 KB.
union SMem {
  u16 sB[2][2][8][512];     // mfmaD staging: 32768 B
  u16 z[8][2048];           // selR dense weight rows (fp16), XOR-swizzled: 32768 B
};

// ---------------- kernel 1a: pinv[p] = 1/||pool_p|| ----------------
__global__ __launch_bounds__(256) void k_pinv(const float* __restrict__ pool,
                                              float* __restrict__ pinv) {
  int p = blockIdx.x * 256 + threadIdx.x;
  const float4* row = (const float4*)(pool + (size_t)p * C_DIM);
  float s = 0.f;
#pragma unroll
  for (int i = 0; i < C_DIM / 4; ++i) {
    float4 v = row[i];
    s += v.x * v.x + v.y * v.y + v.z * v.z + v.w * v.w;
  }
  pinv[p] = 1.0f / sqrtf(s);
}

// ------- packpool role: pool*pinv*2^8 into MFMA-A frag order (ah/al, K=c),
//         plus raw fp16 pool^T in MFMA-A frag order with K=p (phT) for the
//         recon MFMA. 128 blocks x 512 threads. ------------------------------
// ah/al frag (pm,ks,lane,j): p = pm*16 + (lane&15), c = ks*32 + (lane>>4)*8 + j
// phT  frag (pm,ks,lane,j): c = pm*16 + (lane&15), p = ks*32 + (lane>>4)*8 + j
__device__ __forceinline__ void packpool_body(int b,
                                              const float* __restrict__ pool,
                                              const float* __restrict__ pinv,
                                              u16* __restrict__ ah,
                                              u16* __restrict__ al,
                                              u16* __restrict__ phT) {
  int tid = b * 512 + threadIdx.x;              // 65536 = 128*8*64
  int lane = tid & 63;
  int ks = (tid >> 6) & 7;
  int pm = tid >> 9;
  int p = pm * 16 + (lane & 15);
  int c0 = ks * 32 + ((lane >> 4) << 3);
  float sc = pinv[p] * SCALE;
  const float* src = pool + (size_t)p * C_DIM + c0;
  u16 h8[8], l8[8], p8[8];
#pragma unroll
  for (int j = 0; j < 8; ++j) {
    float raw = src[j];
    p8[j] = __half_as_ushort(__float2half(raw));
    float v = raw * sc;
    u16 h = f2h_ftz(v);
    float r = v - __half2float(__ushort_as_half(h));  // exact (Sterbenz range)
    h8[j] = h;
    l8[j] = f2h_ftz(r);
  }
  size_t o = (size_t)tid * 8;
  st8(ah + o, h8); st8(al + o, l8);
  // phT transpose-scatter: element (c=c0+i, p)
  {
    int ksr = p >> 5, lhr = (p >> 3) & 3, jr = p & 7;
#pragma unroll
    for (int i = 0; i < 8; ++i) {
      int c = c0 + i;
      size_t idx = ((size_t)((c >> 4) * 64 + ksr) * 64 + ((c & 15) + 16 * lhr)) * 8 + jr;
      phT[idx] = p8[i];
    }
  }
}

// ------- packx role: x*2^8 into MFMA-B frag order, fp16 hi/lo split ---------
// One quarter = 256 blocks x 512 threads; block pb packs pn = pq*256 + pb.
// frag element (pn, ks, lane, j): pix = pn*16 + (lane&15), c = ks*32 + (lane>>4)*8 + j
__device__ __forceinline__ void packx_body(int pb, int pq,
                                           const float* __restrict__ x,
                                           u16* __restrict__ xh,
                                           u16* __restrict__ xl) {
  int t = threadIdx.x;
  int lane = t & 63;
  int ks = (t >> 6) & 7;
  int pn = pq * 256 + pb;
  int pix = pn * 16 + (lane & 15);
  int n = pix >> 10, l = pix & 1023;
  int c0 = ks * 32 + ((lane >> 4) << 3);
  const float* src = x + ((size_t)(n * C_DIM + c0)) * L_DIM + l;
  u16 h8[8], l8[8];
#pragma unroll
  for (int j = 0; j < 8; ++j) {
    float v = src[(size_t)j * L_DIM] * SCALE;
    u16 h = f2h_ftz(v);
    float r = v - __half2float(__ushort_as_half(h));
    h8[j] = h;
    l8[j] = f2h_ftz(r);
  }
  size_t o = ((size_t)pn * 512 + (size_t)ks * 64 + lane) * 8;
  st8(xh + o, h8); st8(xl + o, l8);
}

// ------- prologue kernel: packpool (b<128) + packx quarter 0 (b>=128) -------
__global__ __launch_bounds__(512) void k_pre(const float* __restrict__ pool,
                                             const float* __restrict__ pinv,
                                             u16* __restrict__ ah,
                                             u16* __restrict__ al,
                                             u16* __restrict__ phT,
                                             const float* __restrict__ x,
                                             u16* __restrict__ xh,
                                             u16* __restrict__ xl) {
  int b = blockIdx.x;
  if (b < 128) packpool_body(b, pool, pinv, ah, al, phT);
  else packx_body(b - 128, 0, x, xh, xl);
}

// ---------------- mfmaD role: sbuf[pixLocal][p], one quarter (4096 pix) ------
// 512 blocks = pT(16) x pixT(32); 512 thr / 8 waves, wave owns 1 pm (16 P rows).
// B fragments staged to LDS via global_load_lds, double-buffered 2-phase
// pipeline: stage(ks+1) || compute(ks); one barrier/iter.
__device__ __forceinline__ void mfma_body(int b, int mq,
                                          const u16* __restrict__ ah_,
                                          const u16* __restrict__ al_,
                                          const u16* __restrict__ xh_,
                                          const u16* __restrict__ xl_,
                                          float* __restrict__ sbuf,
                                          u16 (*sB)[2][8][512]) {
  const int t = threadIdx.x, lane = t & 63, w = t >> 6;     // w 0..7
  const int pT = b & 15, pixT = b >> 4;                     // pixT 0..31
  const int pm = pT * 8 + w;
  const int pnBase = mq * 256 + pixT * 8;
  const half8* A8h = (const half8*)ah_;
  const half8* A8l = (const half8*)al_;
  const u16* xsrc[2] = {xh_, xl_};

  floatx4 acc[8];
#pragma unroll
  for (int nt = 0; nt < 8; ++nt) acc[nt] = (floatx4){0.f, 0.f, 0.f, 0.f};

  // prologue: stage slab ks=0 into buffer 0 (16 rows over 8 waves = 2/wave)
#pragma unroll
  for (int q = 0; q < 2; ++q) {
    int id = w * 2 + q;
    int arr = id >> 3, nt = id & 7;
    gl_lds16(xsrc[arr] + ((size_t)(pnBase + nt) * 512 + lane) * 8,
             &sB[0][arr][nt][0]);
  }
  __syncthreads();

#pragma unroll 1
  for (int ks = 0; ks < 8; ++ks) {
    const int cur = ks & 1;
    half8 aH, aL;
    {
      size_t idx = (size_t)pm * 512 + (size_t)ks * 64 + lane;
      aH = A8h[idx]; aL = A8l[idx];
    }
    if (ks < 7) {
#pragma unroll
      for (int q = 0; q < 2; ++q) {
        int id = w * 2 + q;
        int arr = id >> 3, nt = id & 7;
        gl_lds16(xsrc[arr] + ((size_t)(pnBase + nt) * 512 + (ks + 1) * 64 + lane) * 8,
                 &sB[cur ^ 1][arr][nt][0]);
      }
    }
#pragma unroll
    for (int nt = 0; nt < 8; ++nt) {
      half8 bh = *(const half8*)&sB[cur][0][nt][lane * 8];
      half8 bl = *(const half8*)&sB[cur][1][nt][lane * 8];
      floatx4 c = acc[nt];
      c = __builtin_amdgcn_mfma_f32_16x16x32_f16(aH, bh, c, 0, 0, 0);
      c = __builtin_amdgcn_mfma_f32_16x16x32_f16(aH, bl, c, 0, 0, 0);
      c = __builtin_amdgcn_mfma_f32_16x16x32_f16(aL, bh, c, 0, 0, 0);
      acc[nt] = c;
    }
    __syncthreads();   // drains staged loads + protects buffer reuse
  }

  const int qr = lane >> 4, cl = lane & 15;
  const int pix0 = pixT * 128;
  const int pcol = pT * 128 + w * 16;
#pragma unroll
  for (int nt = 0; nt < 8; ++nt) {
    float* dst = sbuf + (size_t)(pix0 + nt * 16 + cl) * P_DIM + pcol + qr * 4;
    *(float4*)dst = make_float4(acc[nt][0], acc[nt][1], acc[nt][2], acc[nt][3]);
  }
}

// ------------- selR role: top-102 select -> dense z (LDS) -> MFMA recon ------
// One quarter. 512 blocks x 512 thr (8 waves); wave wv owns pixel gp0+wv.
// Phase 1 (per wave): load sbuf row, exact threshold search, kept masks,
//   Ssum -> invS, write dense z row: z[wv][p] = kept ? fp16(invS*w) : 0.
//   Lane owns p = q*256 + lane*4 + rr (32 values) -> 8x 8B LDS stores.
//   No compaction/scatter/gather at all.
// Phase 2 (block): out[:,8 px] = phT^T @ z via MFMA. wave wv -> pm {2wv,2wv+1},
//   64 ks steps over K=p. B-frag col = lane&15 -> px (cols 8-15 read dup rows,
//   outputs ignored). z rows XOR-swizzled (byte ^= row<<4) -> conflict-free.
__device__ __forceinline__ void selr_body(int b, int sq,
                                          const float* __restrict__ sbuf,
                                          const u16* __restrict__ phT,
                                          float* __restrict__ out,
                                          u16 (*z)[2048]) {
  const int t = threadIdx.x;
  const int lane = t & 63;
  const int wv = t >> 6;
  const int gp0 = sq * QTR_PIX + b * 8;
  const float* sp = sbuf + (size_t)(b * 8 + wv) * P_DIM;

  float4 v[8];
#pragma unroll
  for (int q = 0; q < 8; ++q) v[q] = *(const float4*)(sp + q * 256 + lane * 4);

  // ---- wave max of |s| ----
  float M = 0.f;
#pragma unroll
  for (int q = 0; q < 8; ++q) {
    M = fmaxf(M, fabsf(v[q].x)); M = fmaxf(M, fabsf(v[q].y));
    M = fmaxf(M, fabsf(v[q].z)); M = fmaxf(M, fabsf(v[q].w));
  }
#pragma unroll
  for (int off = 1; off < 64; off <<= 1) M = fmaxf(M, __shfl_xor(M, off));
  const unsigned bitsM = __float_as_uint(M);

  auto countGE = [&](float mf) -> unsigned {
    unsigned cnt = 0;
#pragma unroll
    for (int q = 0; q < 8; ++q) {
      cnt += (unsigned)__popcll(__ballot(fabsf(v[q].x) >= mf));
      cnt += (unsigned)__popcll(__ballot(fabsf(v[q].y) >= mf));
      cnt += (unsigned)__popcll(__ballot(fabsf(v[q].z) >= mf));
      cnt += (unsigned)__popcll(__ballot(fabsf(v[q].w) >= mf));
    }
    return cnt;
  };

  // ---- quad-probe seed + false-position/bisection exact search (r6) ----
  const unsigned t1 = (bitsM > (1u << 23)) ? bitsM - (1u << 23) : 1u;
  const unsigned t2 = (bitsM > (2u << 23)) ? bitsM - (2u << 23) : 1u;
  const unsigned t3 = (bitsM > (3u << 23)) ? bitsM - (3u << 23) : 1u;
  const unsigned t4 = (bitsM > (5u << 23)) ? bitsM - (5u << 23) : 1u;
  const float g1 = __uint_as_float(t1), g2 = __uint_as_float(t2);
  const float g3 = __uint_as_float(t3), g4 = __uint_as_float(t4);
  unsigned c1 = 0, c2 = 0, c3 = 0, c4 = 0;
#pragma unroll
  for (int q = 0; q < 8; ++q) {
    const float* f = (const float*)&v[q];
#pragma unroll
    for (int rr = 0; rr < 4; ++rr) {
      float av = fabsf(f[rr]);
      c1 += (unsigned)__popcll(__ballot(av >= g1));
      c2 += (unsigned)__popcll(__ballot(av >= g2));
      c3 += (unsigned)__popcll(__ballot(av >= g3));
      c4 += (unsigned)__popcll(__ballot(av >= g4));
    }
  }

  unsigned lo = 0u, hi = 1u, cl_ = P_DIM, ch_ = 0u;
  bool exact = false;
  if (c1 == (unsigned)KEEP)      { lo = t1; exact = true; }
  else if (c2 == (unsigned)KEEP) { lo = t2; exact = true; }
  else if (c3 == (unsigned)KEEP) { lo = t3; exact = true; }
  else if (c4 == (unsigned)KEEP) { lo = t4; exact = true; }
  else if (c1 > (unsigned)KEEP)  { lo = t1; cl_ = c1; hi = bitsM + 1u; ch_ = 0u; }
  else if (c2 > (unsigned)KEEP)  { lo = t2; cl_ = c2; hi = t1; ch_ = c1; }
  else if (c3 > (unsigned)KEEP)  { lo = t3; cl_ = c3; hi = t2; ch_ = c2; }
  else if (c4 > (unsigned)KEEP)  { lo = t4; cl_ = c4; hi = t3; ch_ = c3; }
  else                           { lo = 0u; cl_ = P_DIM; hi = t4; ch_ = c4; }

  int it = 0;
  while (!exact && hi - lo > 1u) {
    unsigned span = hi - lo;
    unsigned step;
    if ((it++ & 1) == 0) {
      step = (unsigned)((float)span * (float)(cl_ - KEEP) / (float)(cl_ - ch_));
    } else {
      step = span >> 1;
    }
    if (step < 1u) step = 1u;
    else if (step > span - 1u) step = span - 1u;
    unsigned m = lo + step;
    unsigned cnt = countGE(__uint_as_float(m));
    if (cnt == (unsigned)KEEP) { lo = m; exact = true; break; }
    if (cnt > (unsigned)KEEP) { lo = m; cl_ = cnt; } else { hi = m; ch_ = cnt; }
  }
  const float V = __uint_as_float(lo);
  const float Vp = exact ? V : __uint_as_float(lo + 1u);

  unsigned rrem = 0u;
  if (!exact) {
    unsigned gt = countGE(Vp);
    rrem = (unsigned)KEEP - gt;
  }

  unsigned km[8];
#pragma unroll
  for (int q = 0; q < 8; ++q) {
    const float* f = (const float*)&v[q];
    unsigned gm = 0;
#pragma unroll
    for (int rr = 0; rr < 4; ++rr)
      if (fabsf(f[rr]) >= Vp) gm |= (1u << rr);
    km[q] = gm;
  }
  if (rrem != 0u) {          // tie handling, p-index order (rare, wave-uniform)
    const unsigned long long lowm = (1ull << lane) - 1ull;
    unsigned tiebase = 0;
#pragma unroll
    for (int q = 0; q < 8; ++q) {
      const float* f = (const float*)&v[q];
      unsigned tm = 0;
#pragma unroll
      for (int rr = 0; rr < 4; ++rr) {
        float av = fabsf(f[rr]);
        if (av >= V && av < Vp) tm |= (1u << rr);
      }
      unsigned teq = 0, myeqb = 0;
#pragma unroll
      for (int rr = 0; rr < 4; ++rr) {
        unsigned long long beq = __ballot((tm >> rr) & 1u);
        teq += (unsigned)__popcll(beq);
        myeqb += (unsigned)__popcll(beq & lowm);
      }
      unsigned cum = 0;
#pragma unroll
      for (int rr = 0; rr < 4; ++rr) {
        if ((tm >> rr) & 1u) {
          if (tiebase + myeqb + cum < rrem) km[q] |= (1u << rr);
          ++cum;
        }
      }
      tiebase += teq;
    }
  }

  float Ssum = 0.f;
#pragma unroll
  for (int q = 0; q < 8; ++q) {
    const float* f = (const float*)&v[q];
#pragma unroll
    for (int rr = 0; rr < 4; ++rr)
      if ((km[q] >> rr) & 1u) Ssum += f[rr];
  }
#pragma unroll
  for (int off = 1; off < 64; off <<= 1) Ssum += __shfl_xor(Ssum, off);
  const float invS = 1.0f / Ssum;

  // ---- write dense z row (XOR-swizzled: byte ^= wv<<4) ----
  {
    char* zr = (char*)&z[wv][0];
#pragma unroll
    for (int q = 0; q < 8; ++q) {
      const float* f = (const float*)&v[q];
      u16 h4[4];
#pragma unroll
      for (int rr = 0; rr < 4; ++rr) {
        float val = ((km[q] >> rr) & 1u) ? invS * f[rr] : 0.f;
        h4[rr] = __half_as_ushort(__float2half(val));
      }
      unsigned w0 = (unsigned)h4[0] | ((unsigned)h4[1] << 16);
      unsigned w1 = (unsigned)h4[2] | ((unsigned)h4[3] << 16);
      *(uint2*)(zr + ((q * 512 + lane * 8) ^ (wv << 4))) = make_uint2(w0, w1);
    }
  }
  __syncthreads();

  // ---- MFMA recon: out[c][px] = sum_p phT[c][p] * z[px][p] ----
  const half8* A = (const half8*)phT;           // [pm][ks][lane] half8
  const int pm0 = wv * 2;
  const int zrow = lane & 7;                    // col&7 (cols 8-15 dup, ignored)
  const char* zb = (const char*)&z[zrow][0];
  const int boff = ((lane >> 4) << 4);          // (lane>>4)*8 u16 = 16 bytes

  floatx4 acc0 = (floatx4){0.f, 0.f, 0.f, 0.f};
  floatx4 acc1 = (floatx4){0.f, 0.f, 0.f, 0.f};
#pragma unroll 8
  for (int ks = 0; ks < 64; ++ks) {
    half8 bz = *(const half8*)(zb + ((ks * 64 + boff) ^ (zrow << 4)));
    half8 a0 = A[(size_t)(pm0 * 64 + ks) * 64 + lane];
    half8 a1 = A[(size_t)((pm0 + 1) * 64 + ks) * 64 + lane];
    acc0 = __builtin_amdgcn_mfma_f32_16x16x32_f16(a0, bz, acc0, 0, 0, 0);
    acc1 = __builtin_amdgcn_mfma_f32_16x16x32_f16(a1, bz, acc1, 0, 0, 0);
  }

  const int col = lane & 15;
  if (col < 8) {
    int pix = gp0 + col;
    int n = pix >> 10, l = pix & 1023;
    int r0 = (lane >> 4) * 4;
#pragma unroll
    for (int r = 0; r < 4; ++r) {
      int c = pm0 * 16 + r0 + r;
      out[((size_t)(n * C_DIM + c)) * L_DIM + l] = acc0[r];
      out[((size_t)(n * C_DIM + c + 16)) * L_DIM + l] = acc1[r];
    }
  }
}

// ---------------- fused pipeline kernel --------------------------------------
// Block roles (in grid order): selR(sq) [512] | packx(pq) [256] | mfmaD(mq) [512].
// sbuf slot = quarter & 1; launch order guarantees mfmaD(q) precedes selR(q);
// packx(q) completes one dispatch before mfmaD(q) consumes it.
__global__ __launch_bounds__(512, 4) void k_main(const u16* __restrict__ ah_,
                                                 const u16* __restrict__ al_,
                                                 const u16* __restrict__ xh_,
                                                 const u16* __restrict__ xl_,
                                                 const u16* __restrict__ phT,
                                                 const float* __restrict__ x,
                                                 float* __restrict__ sbuf0,
                                                 float* __restrict__ sbuf1,
                                                 float* __restrict__ out,
                                                 int mq, int sq, int pq) {
  __shared__ __align__(16) SMem sm;
  const int b = blockIdx.x;
  const int nsel = (sq >= 0) ? 512 : 0;
  const int npk = (pq >= 0) ? 256 : 0;
  if (b < nsel) {
    selr_body(b, sq, (sq & 1) ? sbuf1 : sbuf0, phT, out, sm.z);
  } else if (b < nsel + npk) {
    packx_body(b - nsel, pq, x, (u16*)xh_, (u16*)xl_);
  } else {
    mfma_body(b - nsel - npk, mq, ah_, al_, xh_, xl_, (mq & 1) ? sbuf1 : sbuf0, sm.sB);
  }
}

// ---------------- launch ----------------
// d_ws layout (~83 MB):
//   sbuf0 33,554,432 | sbuf1 33,554,432 | xh/xl 2 x 8,388,608
//   ah/al 2 x 1,048,576 | phT 1,048,576 | pinv 8,192
extern "C" void kernel_launch(void* const* d_in, const int* in_sizes, int n_in,
                              void* d_out, int out_size, void* d_ws, size_t ws_size,
                              hipStream_t stream) {
  const float* x = (const float*)d_in[0];
  const float* pool = (const float*)d_in[1];
  float* out = (float*)d_out;
  char* wsb = (char*)d_ws;
  float* sbuf0 = (float*)wsb;
  float* sbuf1 = (float*)(wsb + 33554432);
  u16* xh = (u16*)(wsb + 67108864);
  u16* xl = xh + 4194304;
  u16* ah = xl + 4194304;
  u16* al = ah + 524288;
  u16* phT = al + 524288;
  float* pinv = (float*)(phT + 524288);

  k_pinv<<<P_DIM / 256, 256, 0, stream>>>(pool, pinv);
  k_pre<<<384, 512, 0, stream>>>(pool, pinv, ah, al, phT, x, xh, xl);

  k_main<<<768, 512, 0, stream>>>(ah, al, xh, xl, phT, x, sbuf0, sbuf1, out, 0, -1, 1);
  k_main<<<1280, 512, 0, stream>>>(ah, al, xh, xl, phT, x, sbuf0, sbuf1, out, 1, 0, 2);
  k_main<<<1280, 512, 0, stream>>>(ah, al, xh, xl, phT, x, sbuf0, sbuf1, out, 2, 1, 3);
  k_main<<<1024, 512, 0, stream>>>(ah, al, xh, xl, phT, x, sbuf0, sbuf1, out, 3, 2, -1);
  k_main<<<512, 512, 0, stream>>>(ah, al, xh, xl, phT, x, sbuf0, sbuf1, out, -1, 3, -1);
}

// Round 11
// 252.066 us; speedup vs baseline: 1.1011x; 1.1011x over previous
//
#include <hip/hip_runtime.h>
#include <hip/hip_fp16.h>

typedef unsigned short u16;
typedef _Float16 half8 __attribute__((ext_vector_type(8)));
typedef float floatx4 __attribute__((ext_vector_type(4)));

#define C_DIM 256
#define P_DIM 2048
#define L_DIM 1024
#define N_DIM 16
#define KEEP 102
#define KPAD 104
#define QTR_PIX 4096    // pixels per quarter-pass
#define SCALE 256.0f    // 2^8 input pre-scale; both operands scaled -> acc at 2^16.
                        // Downstream is scale-invariant (topk order + w/Sum(w)).

__device__ __forceinline__ void st8(u16* dst, const u16* s) {
  uint4 u;
  u.x = (unsigned)s[0] | ((unsigned)s[1] << 16);
  u.y = (unsigned)s[2] | ((unsigned)s[3] << 16);
  u.z = (unsigned)s[4] | ((unsigned)s[5] << 16);
  u.w = (unsigned)s[6] | ((unsigned)s[7] << 16);
  *(uint4*)dst = u;
}

// fp32 -> fp16 with flush-to-zero of subnormal results (MFMA denormal guard).
__device__ __forceinline__ u16 f2h_ftz(float v) {
  if (fabsf(v) < 6.103515625e-5f) return 0;
  return __half_as_ushort(__float2half(v));
}

// async global->LDS, 16B per lane. LDS dest is wave-uniform base + lane*16.
__device__ __forceinline__ void gl_lds16(const u16* g, u16* l) {
  __builtin_amdgcn_global_load_lds(
      (const __attribute__((address_space(1))) unsigned int*)g,
      (__attribute__((address_space(3))) unsigned int*)l, 16, 0, 0);
}

// shared-memory overlay: mfma role needs 32 KB staging, select role ~15 KB
union SMem {
  u16 sB[2][2][8][512];                               // 32768 B
  struct {
    float tbuf[8][260];                               // 8320 B
    int2  kpw[8][KPAD];                               // 6656 B (byte-off, weight)
  } sel;
};

// ---------------- kernel 1a: pinv[p] = 1/||pool_p|| ----------------
__global__ __launch_bounds__(256) void k_pinv(const float* __restrict__ pool,
                                              float* __restrict__ pinv) {
  int p = blockIdx.x * 256 + threadIdx.x;
  const float4* row = (const float4*)(pool + (size_t)p * C_DIM);
  float s = 0.f;
#pragma unroll
  for (int i = 0; i < C_DIM / 4; ++i) {
    float4 v = row[i];
    s += v.x * v.x + v.y * v.y + v.z * v.z + v.w * v.w;
  }
  pinv[p] = 1.0f / sqrtf(s);
}

// ------- packpool role: pool*pinv*2^8 into MFMA-A frag order, fp16 hi/lo,
//         plus raw fp16 pool copy for the recon gather. 128 blocks x 512 thr. --
// frag element (pm, ks, lane, j): p = pm*16 + (lane&15), c = ks*32 + (lane>>4)*8 + j
__device__ __forceinline__ void packpool_body(int b,
                                              const float* __restrict__ pool,
                                              const float* __restrict__ pinv,
                                              u16* __restrict__ ah,
                                              u16* __restrict__ al,
                                              u16* __restrict__ ph) {
  int tid = b * 512 + threadIdx.x;              // 65536 = 128*8*64
  int lane = tid & 63;
  int ks = (tid >> 6) & 7;
  int pm = tid >> 9;
  int p = pm * 16 + (lane & 15);
  int c0 = ks * 32 + ((lane >> 4) << 3);
  float sc = pinv[p] * SCALE;
  const float* src = pool + (size_t)p * C_DIM + c0;
  u16 h8[8], l8[8], p8[8];
#pragma unroll
  for (int j = 0; j < 8; ++j) {
    float raw = src[j];
    p8[j] = __half_as_ushort(__float2half(raw));
    float v = raw * sc;
    u16 h = f2h_ftz(v);
    float r = v - __half2float(__ushort_as_half(h));  // exact (Sterbenz range)
    h8[j] = h;
    l8[j] = f2h_ftz(r);
  }
  size_t o = (size_t)tid * 8;
  st8(ah + o, h8); st8(al + o, l8);
  st8(ph + (size_t)p * C_DIM + c0, p8);
}

// ------- packx role: x*2^8 into MFMA-B frag order, fp16 hi/lo split ---------
// One quarter = 256 blocks x 512 threads; block pb packs pn = pq*256 + pb.
// frag element (pn, ks, lane, j): pix = pn*16 + (lane&15), c = ks*32 + (lane>>4)*8 + j
__device__ __forceinline__ void packx_body(int pb, int pq,
                                           const float* __restrict__ x,
                                           u16* __restrict__ xh,
                                           u16* __restrict__ xl) {
  int t = threadIdx.x;
  int lane = t & 63;
  int ks = (t >> 6) & 7;
  int pn = pq * 256 + pb;
  int pix = pn * 16 + (lane & 15);
  int n = pix >> 10, l = pix & 1023;
  int c0 = ks * 32 + ((lane >> 4) << 3);
  const float* src = x + ((size_t)(n * C_DIM + c0)) * L_DIM + l;
  u16 h8[8], l8[8];
#pragma unroll
  for (int j = 0; j < 8; ++j) {
    float v = src[(size_t)j * L_DIM] * SCALE;
    u16 h = f2h_ftz(v);
    float r = v - __half2float(__ushort_as_half(h));
    h8[j] = h;
    l8[j] = f2h_ftz(r);
  }
  size_t o = ((size_t)pn * 512 + (size_t)ks * 64 + lane) * 8;
  st8(xh + o, h8); st8(xl + o, l8);
}

// ------- prologue kernel: packpool (b<128) + packx quarter 0 (b>=128) -------
__global__ __launch_bounds__(512) void k_pre(const float* __restrict__ pool,
                                             const float* __restrict__ pinv,
                                             u16* __restrict__ ah,
                                             u16* __restrict__ al,
                                             u16* __restrict__ ph,
                                             const float* __restrict__ x,
                                             u16* __restrict__ xh,
                                             u16* __restrict__ xl) {
  int b = blockIdx.x;
  if (b < 128) packpool_body(b, pool, pinv, ah, al, ph);
  else packx_body(b - 128, 0, x, xh, xl);
}

// ---------------- mfma role: sbuf[pixLocal][p], one quarter (4096 pix) -------
// 512 blocks = pT(16) x pixT(32); 512 thr / 8 waves, wave owns 1 pm (16 P rows).
// B fragments staged to LDS via global_load_lds, double-buffered 2-phase
// pipeline: stage(ks+1) || compute(ks); one barrier/iter.
__device__ __forceinline__ void mfma_body(int b, int mq,
                                          const u16* __restrict__ ah_,
                                          const u16* __restrict__ al_,
                                          const u16* __restrict__ xh_,
                                          const u16* __restrict__ xl_,
                                          float* __restrict__ sbuf,
                                          u16 (*sB)[2][8][512]) {
  const int t = threadIdx.x, lane = t & 63, w = t >> 6;     // w 0..7
  const int pT = b & 15, pixT = b >> 4;                     // pixT 0..31
  const int pm = pT * 8 + w;
  const int pnBase = mq * 256 + pixT * 8;
  const half8* A8h = (const half8*)ah_;
  const half8* A8l = (const half8*)al_;
  const u16* xsrc[2] = {xh_, xl_};

  floatx4 acc[8];
#pragma unroll
  for (int nt = 0; nt < 8; ++nt) acc[nt] = (floatx4){0.f, 0.f, 0.f, 0.f};

  // prologue: stage slab ks=0 into buffer 0 (16 rows over 8 waves = 2/wave)
#pragma unroll
  for (int q = 0; q < 2; ++q) {
    int id = w * 2 + q;
    int arr = id >> 3, nt = id & 7;
    gl_lds16(xsrc[arr] + ((size_t)(pnBase + nt) * 512 + lane) * 8,
             &sB[0][arr][nt][0]);
  }
  __syncthreads();

#pragma unroll 1
  for (int ks = 0; ks < 8; ++ks) {
    const int cur = ks & 1;
    half8 aH, aL;
    {
      size_t idx = (size_t)pm * 512 + (size_t)ks * 64 + lane;
      aH = A8h[idx]; aL = A8l[idx];
    }
    if (ks < 7) {
#pragma unroll
      for (int q = 0; q < 2; ++q) {
        int id = w * 2 + q;
        int arr = id >> 3, nt = id & 7;
        gl_lds16(xsrc[arr] + ((size_t)(pnBase + nt) * 512 + (ks + 1) * 64 + lane) * 8,
                 &sB[cur ^ 1][arr][nt][0]);
      }
    }
#pragma unroll
    for (int nt = 0; nt < 8; ++nt) {
      half8 bh = *(const half8*)&sB[cur][0][nt][lane * 8];
      half8 bl = *(const half8*)&sB[cur][1][nt][lane * 8];
      floatx4 c = acc[nt];
      c = __builtin_amdgcn_mfma_f32_16x16x32_f16(aH, bh, c, 0, 0, 0);
      c = __builtin_amdgcn_mfma_f32_16x16x32_f16(aH, bl, c, 0, 0, 0);
      c = __builtin_amdgcn_mfma_f32_16x16x32_f16(aL, bh, c, 0, 0, 0);
      acc[nt] = c;
    }
    __syncthreads();   // drains staged loads + protects buffer reuse
  }

  const int qr = lane >> 4, cl = lane & 15;
  const int pix0 = pixT * 128;
  const int pcol = pT * 128 + w * 16;
#pragma unroll
  for (int nt = 0; nt < 8; ++nt) {
    float* dst = sbuf + (size_t)(pix0 + nt * 16 + cl) * P_DIM + pcol + qr * 4;
    *(float4*)dst = make_float4(acc[nt][0], acc[nt][1], acc[nt][2], acc[nt][3]);
  }
}

// ---------------- select role: per-pixel top-102 + renorm + recon -----------
// One quarter. 512 blocks; 512 threads = 8 waves; wave wv owns one pixel.
// value (q, rr) at lane: p = q*256 + lane*4 + rr
// LANE-LOCAL lowering: all counting done as per-lane partial counts
// (cmp+add, no ballots) + one shfl_xor butterfly; compaction via per-lane
// kept-count + shfl_up exclusive scan (ballot machinery only in rare tie path).
__device__ __forceinline__ void select_body(int b, int sq,
                                            const float* __restrict__ sbuf,
                                            const u16* __restrict__ pool_h,
                                            float* __restrict__ out,
                                            float (*tbuf)[260],
                                            int2 (*kpw)[KPAD]) {
  const int t = threadIdx.x;
  const int lane = t & 63;
  const int wv = t >> 6;
  const int gp0 = sq * QTR_PIX + b * 8;
  const int n = gp0 >> 10;
  const int l0 = gp0 & 1023;
  const float* sp = sbuf + (size_t)(b * 8 + wv) * P_DIM;

  float4 v[8];
#pragma unroll
  for (int q = 0; q < 8; ++q) v[q] = *(const float4*)(sp + q * 256 + lane * 4);

  if (lane < KPAD - KEEP) kpw[wv][KEEP + lane] = make_int2(0, 0);

  // ---- wave max of |s| ----
  float M = 0.f;
#pragma unroll
  for (int q = 0; q < 8; ++q) {
    M = fmaxf(M, fabsf(v[q].x)); M = fmaxf(M, fabsf(v[q].y));
    M = fmaxf(M, fabsf(v[q].z)); M = fmaxf(M, fabsf(v[q].w));
  }
#pragma unroll
  for (int off = 1; off < 64; off <<= 1) M = fmaxf(M, __shfl_xor(M, off));
  const unsigned bitsM = __float_as_uint(M);

  // per-lane partial count of |v| >= mf (2 VALU/element, no ballot/popc)
  auto cntLocal = [&](float mf) -> unsigned {
    unsigned c = 0;
#pragma unroll
    for (int q = 0; q < 8; ++q) {
      c += (fabsf(v[q].x) >= mf) ? 1u : 0u;
      c += (fabsf(v[q].y) >= mf) ? 1u : 0u;
      c += (fabsf(v[q].z) >= mf) ? 1u : 0u;
      c += (fabsf(v[q].w) >= mf) ? 1u : 0u;
    }
    return c;
  };
  auto wredu = [&](unsigned c) -> unsigned {
#pragma unroll
    for (int off = 1; off < 64; off <<= 1) c += (unsigned)__shfl_xor((int)c, off);
    return c;
  };

  // ---- quad-probe seed: one fused pass over {M/2, M/4, M/8, M/32},
  //      2 counts packed per 32-bit word (sum <= 2048 < 2^16) ----
  const unsigned t1 = (bitsM > (1u << 23)) ? bitsM - (1u << 23) : 1u;
  const unsigned t2 = (bitsM > (2u << 23)) ? bitsM - (2u << 23) : 1u;
  const unsigned t3 = (bitsM > (3u << 23)) ? bitsM - (3u << 23) : 1u;
  const unsigned t4 = (bitsM > (5u << 23)) ? bitsM - (5u << 23) : 1u;
  const float g1 = __uint_as_float(t1), g2 = __uint_as_float(t2);
  const float g3 = __uint_as_float(t3), g4 = __uint_as_float(t4);
  unsigned p12 = 0, p34 = 0;
#pragma unroll
  for (int q = 0; q < 8; ++q) {
    const float* f = (const float*)&v[q];
#pragma unroll
    for (int rr = 0; rr < 4; ++rr) {
      float av = fabsf(f[rr]);
      p12 += (av >= g1) ? 1u : 0u;
      p12 += (av >= g2) ? 0x10000u : 0u;
      p34 += (av >= g3) ? 1u : 0u;
      p34 += (av >= g4) ? 0x10000u : 0u;
    }
  }
  p12 = wredu(p12); p34 = wredu(p34);
  const unsigned c1 = p12 & 0xffffu, c2 = p12 >> 16;
  const unsigned c3 = p34 & 0xffffu, c4 = p34 >> 16;

  // invariant: count(>=lo) >= KEEP > count(>=hi). exact: count == KEEP ->
  // probe IS a valid threshold (kept set == the KEEP largest), no ties.
  unsigned lo = 0u, hi = 1u, cl_ = P_DIM, ch_ = 0u;
  bool exact = false;
  if (c1 == (unsigned)KEEP)      { lo = t1; exact = true; }
  else if (c2 == (unsigned)KEEP) { lo = t2; exact = true; }
  else if (c3 == (unsigned)KEEP) { lo = t3; exact = true; }
  else if (c4 == (unsigned)KEEP) { lo = t4; exact = true; }
  else if (c1 > (unsigned)KEEP)  { lo = t1; cl_ = c1; hi = bitsM + 1u; ch_ = 0u; }
  else if (c2 > (unsigned)KEEP)  { lo = t2; cl_ = c2; hi = t1; ch_ = c1; }
  else if (c3 > (unsigned)KEEP)  { lo = t3; cl_ = c3; hi = t2; ch_ = c2; }
  else if (c4 > (unsigned)KEEP)  { lo = t4; cl_ = c4; hi = t3; ch_ = c3; }
  else                           { lo = 0u; cl_ = P_DIM; hi = t4; ch_ = c4; }

  int it = 0;
  while (!exact && hi - lo > 1u) {
    unsigned span = hi - lo;
    unsigned step;
    if ((it++ & 1) == 0) {
      step = (unsigned)((float)span * (float)(cl_ - KEEP) / (float)(cl_ - ch_));
    } else {
      step = span >> 1;
    }
    if (step < 1u) step = 1u;
    else if (step > span - 1u) step = span - 1u;
    unsigned m = lo + step;
    unsigned cnt = wredu(cntLocal(__uint_as_float(m)));
    if (cnt == (unsigned)KEEP) { lo = m; exact = true; break; }
    if (cnt > (unsigned)KEEP) { lo = m; cl_ = cnt; } else { hi = m; ch_ = cnt; }
  }
  const float V = __uint_as_float(lo);
  const float Vp = exact ? V : __uint_as_float(lo + 1u);

  unsigned rrem = 0u;
  if (!exact) {
    unsigned gt = wredu(cntLocal(Vp));
    rrem = (unsigned)KEEP - gt;
  }

  // ---- kept masks ----
  unsigned km[8];
#pragma unroll
  for (int q = 0; q < 8; ++q) {
    const float* f = (const float*)&v[q];
    unsigned gm = 0;
#pragma unroll
    for (int rr = 0; rr < 4; ++rr)
      if (fabsf(f[rr]) >= Vp) gm |= (1u << rr);
    km[q] = gm;
  }
  if (rrem != 0u) {          // tie handling, p-index order (rare, wave-uniform)
    const unsigned long long lowm = (1ull << lane) - 1ull;
    unsigned tiebase = 0;
#pragma unroll
    for (int q = 0; q < 8; ++q) {
      const float* f = (const float*)&v[q];
      unsigned tm = 0;
#pragma unroll
      for (int rr = 0; rr < 4; ++rr) {
        float av = fabsf(f[rr]);
        if (av >= V && av < Vp) tm |= (1u << rr);
      }
      unsigned teq = 0, myeqb = 0;
#pragma unroll
      for (int rr = 0; rr < 4; ++rr) {
        unsigned long long beq = __ballot((tm >> rr) & 1u);
        teq += (unsigned)__popcll(beq);
        myeqb += (unsigned)__popcll(beq & lowm);
      }
      unsigned cum = 0;
#pragma unroll
      for (int rr = 0; rr < 4; ++rr) {
        if ((tm >> rr) & 1u) {
          if (tiebase + myeqb + cum < rrem) km[q] |= (1u << rr);
          ++cum;
        }
      }
      tiebase += teq;
    }
  }

  // ---- per-lane kept count + local sum ----
  unsigned kc = 0;
  float Sloc = 0.f;
#pragma unroll
  for (int q = 0; q < 8; ++q) {
    const float* f = (const float*)&v[q];
#pragma unroll
    for (int rr = 0; rr < 4; ++rr)
      if ((km[q] >> rr) & 1u) { ++kc; Sloc += f[rr]; }
  }

  // exclusive scan of kc over lanes -> write base
  unsigned inc = kc;
#pragma unroll
  for (int off = 1; off < 64; off <<= 1) {
    unsigned tmp = (unsigned)__shfl_up((int)inc, off);
    if (lane >= off) inc += tmp;
  }
  unsigned pos = inc - kc;

  float Ssum = Sloc;
#pragma unroll
  for (int off = 1; off < 64; off <<= 1) Ssum += __shfl_xor(Ssum, off);
  const float invS = 1.0f / Ssum;

  // ---- compacted write (lane-major order; recon is order-invariant) ----
#pragma unroll
  for (int q = 0; q < 8; ++q) {
    const float* f = (const float*)&v[q];
#pragma unroll
    for (int rr = 0; rr < 4; ++rr) {
      if ((km[q] >> rr) & 1u) {
        // PRE-MULTIPLIED byte offset into pool_h (p * 256 u16 * 2B)
        kpw[wv][pos] = make_int2((q * 256 + lane * 4 + rr) << 9,
                                 __float_as_int(f[rr]));
        ++pos;
      }
    }
  }

  __builtin_amdgcn_wave_barrier();

  // ---- recon: out_c = invS * sum_kept s_p * pool_h[p][c], c = 4*lane+j.
  //      fp16 rows (512 B/wave); ping-pong A/B groups of 4, 1-group-ahead
  //      prefetch, v_fma_mix_f32 mixed FMA (r6 proven structure). ----
  float a0 = 0.f, a1 = 0.f, a2 = 0.f, a3 = 0.f;
  const char* pb = (const char*)(pool_h + 4 * lane);
  int2 eA[4], eB[4];
  uint2 rA[4], rB[4];

  auto PROC = [&](const int2* e, const uint2* r) {
#pragma unroll
    for (int j = 0; j < 4; ++j) {
      float w2 = __int_as_float(e[j].y);
      unsigned rx = r[j].x, ry = r[j].y;
      asm volatile("v_fma_mix_f32 %0, %1, %2, %0 op_sel:[0,0,0] op_sel_hi:[0,1,0]"
                   : "+v"(a0) : "v"(w2), "v"(rx));
      asm volatile("v_fma_mix_f32 %0, %1, %2, %0 op_sel:[0,1,0] op_sel_hi:[0,1,0]"
                   : "+v"(a1) : "v"(w2), "v"(rx));
      asm volatile("v_fma_mix_f32 %0, %1, %2, %0 op_sel:[0,0,0] op_sel_hi:[0,1,0]"
                   : "+v"(a2) : "v"(w2), "v"(ry));
      asm volatile("v_fma_mix_f32 %0, %1, %2, %0 op_sel:[0,1,0] op_sel_hi:[0,1,0]"
                   : "+v"(a3) : "v"(w2), "v"(ry));
    }
  };

#pragma unroll
  for (int j = 0; j < 4; ++j) eA[j] = kpw[wv][j];
#pragma unroll
  for (int j = 0; j < 4; ++j) rA[j] = *(const uint2*)(pb + (unsigned)eA[j].x);
  // KPAD = 104 = 13 * 8
#pragma unroll 1
  for (int k = 0; k < KPAD; k += 8) {
    const int kb = k + 4;                       // < KPAD always
#pragma unroll
    for (int j = 0; j < 4; ++j) eB[j] = kpw[wv][kb + j];
#pragma unroll
    for (int j = 0; j < 4; ++j) rB[j] = *(const uint2*)(pb + (unsigned)eB[j].x);
    PROC(eA, rA);
    const int ka = (k + 8 < KPAD) ? k + 8 : 0;  // dummy prefetch on last iter
#pragma unroll
    for (int j = 0; j < 4; ++j) eA[j] = kpw[wv][ka + j];
#pragma unroll
    for (int j = 0; j < 4; ++j) rA[j] = *(const uint2*)(pb + (unsigned)eA[j].x);
    PROC(eB, rB);
  }
  a0 *= invS; a1 *= invS; a2 *= invS; a3 *= invS;

  *(float4*)&tbuf[wv][4 * lane] = make_float4(a0, a1, a2, a3);
  __syncthreads();

  {
    int c = t >> 1, lq = t & 1;
    float4 o = make_float4(tbuf[4 * lq + 0][c], tbuf[4 * lq + 1][c],
                           tbuf[4 * lq + 2][c], tbuf[4 * lq + 3][c]);
    *(float4*)(out + ((size_t)(n * C_DIM + c)) * L_DIM + l0 + 4 * lq) = o;
  }
}

// ---------------- fused pipeline kernel --------------------------------------
// Block roles (in grid order): select(sq) [512] | packx(pq) [256] | mfma(mq) [512].
// sbuf slot = quarter & 1; launch order guarantees mfma(q) precedes select(q);
// packx(q) completes one dispatch before mfma(q) consumes it.
__global__ __launch_bounds__(512, 4) void k_main(const u16* __restrict__ ah_,
                                                 const u16* __restrict__ al_,
                                                 const u16* __restrict__ xh_,
                                                 const u16* __restrict__ xl_,
                                                 const u16* __restrict__ ph,
                                                 const float* __restrict__ x,
                                                 float* __restrict__ sbuf0,
                                                 float* __restrict__ sbuf1,
                                                 float* __restrict__ out,
                                                 int mq, int sq, int pq) {
  __shared__ __align__(16) SMem sm;
  const int b = blockIdx.x;
  const int nsel = (sq >= 0) ? 512 : 0;
  const int npk = (pq >= 0) ? 256 : 0;
  if (b < nsel) {
    select_body(b, sq, (sq & 1) ? sbuf1 : sbuf0, ph, out,
                sm.sel.tbuf, sm.sel.kpw);
  } else if (b < nsel + npk) {
    packx_body(b - nsel, pq, x, (u16*)xh_, (u16*)xl_);
  } else {
    mfma_body(b - nsel - npk, mq, ah_, al_, xh_, xl_, (mq & 1) ? sbuf1 : sbuf0, sm.sB);
  }
}

// ---------------- launch ----------------
// d_ws layout (~83 MB):
//   sbuf0 33,554,432 | sbuf1 33,554,432 | xh/xl 2 x 8,388,608
//   ah/al 2 x 1,048,576 | pool_h 1,048,576 | pinv 8,192
extern "C" void kernel_launch(void* const* d_in, const int* in_sizes, int n_in,
                              void* d_out, int out_size, void* d_ws, size_t ws_size,
                              hipStream_t stream) {
  const float* x = (const float*)d_in[0];
  const float* pool = (const float*)d_in[1];
  float* out = (float*)d_out;
  char* wsb = (char*)d_ws;
  float* sbuf0 = (float*)wsb;
  float* sbuf1 = (float*)(wsb + 33554432);
  u16* xh = (u16*)(wsb + 67108864);
  u16* xl = xh + 4194304;
  u16* ah = xl + 4194304;
  u16* al = ah + 524288;
  u16* ph = al + 524288;
  float* pinv = (float*)(ph + 524288);

  k_pinv<<<P_DIM / 256, 256, 0, stream>>>(pool, pinv);
  k_pre<<<384, 512, 0, stream>>>(pool, pinv, ah, al, ph, x, xh, xl);

  k_main<<<768, 512, 0, stream>>>(ah, al, xh, xl, ph, x, sbuf0, sbuf1, out, 0, -1, 1);
  k_main<<<1280, 512, 0, stream>>>(ah, al, xh, xl, ph, x, sbuf0, sbuf1, out, 1, 0, 2);
  k_main<<<1280, 512, 0, stream>>>(ah, al, xh, xl, ph, x, sbuf0, sbuf1, out, 2, 1, 3);
  k_main<<<1024, 512, 0, stream>>>(ah, al, xh, xl, ph, x, sbuf0, sbuf1, out, 3, 2, -1);
  k_main<<<512, 512, 0, stream>>>(ah, al, xh, xl, ph, x, sbuf0, sbuf1, out, -1, 3, -1);
}